// Round 2
// baseline (418.094 us; speedup 1.0000x reference)
//
#include <hip/hip_runtime.h>
#include <hip/hip_bf16.h>

// ---------------------------------------------------------------------------
// NeighborhoodAttentionBlock: B=2, H=W=64, C=256, nh=4, hd=64, k=7
// Input dtype detected at runtime (fp32 vs bf16) — reference declares fp32,
// harness may convert to bf16. Intermediates fp32 in workspace (~40 MB).
// ---------------------------------------------------------------------------

#define ROWS 8192      // B*H*W
#define C_DIM 256

__device__ __forceinline__ float bf2f(__hip_bfloat16 b) { return __bfloat162float(b); }
__device__ __forceinline__ float us2f(unsigned short u) {
    return __uint_as_float(((unsigned int)u) << 16);
}

template <bool F32>
__device__ __forceinline__ float ldext(const void* p, size_t i) {
    return F32 ? ((const float*)p)[i] : bf2f(((const __hip_bfloat16*)p)[i]);
}

// ---------------------------------------------------------------------------
// Dtype detector: read 64 EVEN uint16 indices of x, count sane bf16 values.
// True bf16 data -> ~64 sane. fp32 data read as bf16 (even idx = mantissa-low
// bits -> uniform exponent) -> ~10 sane. flag=1 means fp32 inputs.
// ---------------------------------------------------------------------------
__global__ __launch_bounds__(64) void detect_kernel(const unsigned short* __restrict__ xu,
                                                    int* __restrict__ flag) {
    const int lane = threadIdx.x;
    const float v = us2f(xu[lane * 62]);          // even index, spread
    const float a = fabsf(v);
    const bool sane = (a < 1e4f) && (a > 1e-8f);  // NaN -> false
    const unsigned long long m = __ballot(sane);
    if (lane == 0) flag[0] = (__popcll(m) < 32) ? 1 : 0;
}

// ---------------------------------------------------------------------------
// RMSNorm (+ optional RoPE2D). One block (256 thr) per pixel row.
// ---------------------------------------------------------------------------
template <bool ROPE, bool IN_EXT, bool F32>
__device__ __forceinline__ void rms_body(const void* __restrict__ in,
                                         const void* __restrict__ w,
                                         float* __restrict__ out) {
    const int row = blockIdx.x;
    const int c = threadIdx.x;
    const size_t idx = (size_t)row * C_DIM + c;
    float v = IN_EXT ? ldext<F32>(in, idx) : ((const float*)in)[idx];

    float s = v * v;
    #pragma unroll
    for (int off = 32; off; off >>= 1) s += __shfl_xor(s, off);
    __shared__ float red[4];
    const int wid = c >> 6;
    if ((c & 63) == 0) red[wid] = s;
    __syncthreads();
    const float sum = red[0] + red[1] + red[2] + red[3];
    const float r = rsqrtf(sum * (1.0f / C_DIM) + 1e-6f);

    float nv = v * r * ldext<F32>(w, c);

    if (ROPE) {
        const int py = (row >> 6) & 63;
        const int px = row & 63;
        const float pos = (c < 128) ? (float)py : (float)px;
        const int j = (c & 127) >> 1;                       // pair index in [0,64)
        const float inv = expf(-(float)j * (9.210340371976184f / 64.0f)); // 10000^(-j/64)
        const float th = pos * inv;
        const float cs = cosf(th), sn = sinf(th);
        const float partner = __shfl_xor(nv, 1);
        nv = ((c & 1) == 0) ? (nv * cs - partner * sn) : (partner * sn + nv * cs);
    }
    out[idx] = nv;
}

template <bool ROPE, bool IN_EXT>
__global__ __launch_bounds__(256) void rmsnorm_kernel(const void* __restrict__ in,
                                                      const void* __restrict__ w,
                                                      float* __restrict__ out,
                                                      const int* __restrict__ flag) {
    if (flag[0]) rms_body<ROPE, IN_EXT, true>(in, w, out);
    else         rms_body<ROPE, IN_EXT, false>(in, w, out);
}

// ---------------------------------------------------------------------------
// Tiled GEMM: C[M,N] = A[M,256] @ W[256,N] (+ epilogue)
//   A fp32 (internal), W external dtype. BM=BN=64, BK=16, 256 thr, 4x4 acc.
// EPI: 0 = store fp32
//      1 = + bias + external residual, store fp32
//      2 = + bias, store fp32
//      3 = + bias + fp32 residual, store external dtype
// ---------------------------------------------------------------------------
template <int EPI, bool F32>
__device__ __forceinline__ void gemm_body(const float* __restrict__ A,
                                          const void* __restrict__ W,
                                          const void* __restrict__ bias,
                                          const void* __restrict__ resid,
                                          void* __restrict__ Cout,
                                          int N) {
    const int K = 256;
    __shared__ float As[16][65];
    __shared__ float Ws[16][65];

    const int tid = threadIdx.x;
    const int tx = tid & 15, ty = tid >> 4;
    const int m0 = blockIdx.y * 64, n0 = blockIdx.x * 64;

    const int am = tid >> 2, ak = (tid & 3) * 4;
    const int wk = tid >> 4, wn = (tid & 15) * 4;

    float acc[4][4] = {};

    for (int k0 = 0; k0 < K; k0 += 16) {
        const float4 av = *(const float4*)(A + (size_t)(m0 + am) * K + k0 + ak);
        As[ak + 0][am] = av.x;
        As[ak + 1][am] = av.y;
        As[ak + 2][am] = av.z;
        As[ak + 3][am] = av.w;

        const size_t woff = (size_t)(k0 + wk) * N + n0 + wn;
        if (F32) {
            const float4 wv = *(const float4*)((const float*)W + woff);
            Ws[wk][wn + 0] = wv.x;
            Ws[wk][wn + 1] = wv.y;
            Ws[wk][wn + 2] = wv.z;
            Ws[wk][wn + 3] = wv.w;
        } else {
            const ushort4 wv = *(const ushort4*)((const unsigned short*)W + woff);
            Ws[wk][wn + 0] = us2f(wv.x);
            Ws[wk][wn + 1] = us2f(wv.y);
            Ws[wk][wn + 2] = us2f(wv.z);
            Ws[wk][wn + 3] = us2f(wv.w);
        }

        __syncthreads();
        #pragma unroll
        for (int kk = 0; kk < 16; ++kk) {
            float a[4], b[4];
            #pragma unroll
            for (int i = 0; i < 4; ++i) a[i] = As[kk][ty * 4 + i];
            #pragma unroll
            for (int j = 0; j < 4; ++j) b[j] = Ws[kk][tx * 4 + j];
            #pragma unroll
            for (int i = 0; i < 4; ++i)
                #pragma unroll
                for (int j = 0; j < 4; ++j) acc[i][j] = fmaf(a[i], b[j], acc[i][j]);
        }
        __syncthreads();
    }

    #pragma unroll
    for (int i = 0; i < 4; ++i) {
        const int m = m0 + ty * 4 + i;
        #pragma unroll
        for (int j = 0; j < 4; ++j) {
            const int n = n0 + tx * 4 + j;
            float v = acc[i][j];
            if (EPI == 1 || EPI == 2 || EPI == 3) v += ldext<F32>(bias, n);
            if (EPI == 1) v += ldext<F32>(resid, (size_t)m * N + n);
            if (EPI == 3) v += ((const float*)resid)[(size_t)m * N + n];
            if (EPI == 3) {
                if (F32) ((float*)Cout)[(size_t)m * N + n] = v;
                else     ((__hip_bfloat16*)Cout)[(size_t)m * N + n] = __float2bfloat16(v);
            } else {
                ((float*)Cout)[(size_t)m * N + n] = v;
            }
        }
    }
}

template <int EPI>
__global__ __launch_bounds__(256) void gemm_k256(const float* __restrict__ A,
                                                 const void* __restrict__ W,
                                                 const void* __restrict__ bias,
                                                 const void* __restrict__ resid,
                                                 void* __restrict__ Cout,
                                                 int N, const int* __restrict__ flag) {
    if (flag[0]) gemm_body<EPI, true>(A, W, bias, resid, Cout, N);
    else         gemm_body<EPI, false>(A, W, bias, resid, Cout, N);
}

// ---------------------------------------------------------------------------
// Neighborhood attention: one wave per (pixel, head). lane = head dim.
// qkv layout: [8192][768] fp32, q at col h*64, k at 256+h*64, v at 512+h*64.
// ---------------------------------------------------------------------------
__global__ __launch_bounds__(256) void attn_kernel(const float* __restrict__ qkv,
                                                   float* __restrict__ ao) {
    __shared__ float slog[4][49];
    const int wid = threadIdx.x >> 6;
    const int lane = threadIdx.x & 63;
    const int g = blockIdx.x * 4 + wid;     // 0..32767
    const int head = g & 3;
    const int pix = g >> 2;                 // 0..8191
    const int px = pix & 63;
    const int py = (pix >> 6) & 63;
    const int b = pix >> 12;

    int sy = py - 3; sy = sy < 0 ? 0 : (sy > 57 ? 57 : sy);
    int sx = px - 3; sx = sx < 0 ? 0 : (sx > 57 ? 57 : sx);

    const float* base = qkv + (size_t)(b * 4096) * 768;
    const int hoff = head * 64;
    const float q = qkv[(size_t)pix * 768 + hoff + lane];

    for (int n = 0; n < 49; ++n) {
        const int ny = sy + n / 7, nx = sx + n % 7;
        const float* kp = base + (size_t)(ny * 64 + nx) * 768 + 256 + hoff;
        float p = q * kp[lane];
        #pragma unroll
        for (int off = 32; off; off >>= 1) p += __shfl_xor(p, off);
        if (lane == 0) slog[wid][n] = p * 0.125f;   // scale = 1/sqrt(64)
    }
    __syncthreads();

    float m = -1e30f;
    for (int n = 0; n < 49; ++n) m = fmaxf(m, slog[wid][n]);

    float sum = 0.0f, acc = 0.0f;
    for (int n = 0; n < 49; ++n) {
        const int ny = sy + n / 7, nx = sx + n % 7;
        const float* vp = base + (size_t)(ny * 64 + nx) * 768 + 512 + hoff;
        const float wgt = expf(slog[wid][n] - m);
        sum += wgt;
        acc = fmaf(wgt, vp[lane], acc);
    }
    ao[(size_t)pix * C_DIM + hoff + lane] = acc / sum;
}

// ---------------------------------------------------------------------------
// GEGLU elementwise: g = gelu_exact(gate) * value
// ---------------------------------------------------------------------------
__global__ __launch_bounds__(256) void geglu_kernel(const float* __restrict__ ffh,
                                                    float* __restrict__ g) {
    const int i = blockIdx.x * 256 + threadIdx.x;     // 0 .. ROWS*256
    const int row = i >> 8, c = i & 255;
    const float gate = ffh[(size_t)row * 512 + c];
    const float val = ffh[(size_t)row * 512 + 256 + c];
    const float ge = 0.5f * gate * (1.0f + erff(gate * 0.70710678118654752f));
    g[i] = ge * val;
}

// ---------------------------------------------------------------------------
extern "C" void kernel_launch(void* const* d_in, const int* in_sizes, int n_in,
                              void* d_out, int out_size, void* d_ws, size_t ws_size,
                              hipStream_t stream) {
    const void* x     = d_in[0];
    const void* n1w   = d_in[1];
    const void* n2w   = d_in[2];
    const void* wqkv  = d_in[3];
    const void* wproj = d_in[4];
    const void* bproj = d_in[5];
    const void* ff1w  = d_in[6];
    const void* ff1b  = d_in[7];
    const void* ff2w  = d_in[8];
    const void* ff2b  = d_in[9];

    // Workspace layout: [flag pad 256B] slotA [8192*256] | qkv [8192*768] | x1 [8192*256]
    int*   flag  = (int*)d_ws;
    float* slotA = (float*)((char*)d_ws + 256);   // h -> ao -> y -> g (serial reuse)
    float* qkv   = slotA + (size_t)ROWS * 256;    // qkv -> ffh (serial reuse)
    float* x1    = qkv + (size_t)ROWS * 768;

    // 0. detect input dtype (fp32 vs bf16)
    detect_kernel<<<1, 64, 0, stream>>>((const unsigned short*)x, flag);
    // 1. h = rope2d(rmsnorm(x, norm1_w))
    rmsnorm_kernel<true, true><<<ROWS, 256, 0, stream>>>(x, n1w, slotA, flag);
    // 2. qkv = h @ w_qkv
    gemm_k256<0><<<dim3(768 / 64, ROWS / 64), 256, 0, stream>>>(slotA, wqkv, nullptr, nullptr, qkv, 768, flag);
    // 3. ao = neighborhood attention(qkv)
    attn_kernel<<<ROWS, 256, 0, stream>>>(qkv, slotA);
    // 4. x1 = x + ao @ w_proj + b_proj
    gemm_k256<1><<<dim3(256 / 64, ROWS / 64), 256, 0, stream>>>(slotA, wproj, bproj, x, x1, 256, flag);
    // 5. y = rmsnorm(x1, norm2_w)
    rmsnorm_kernel<false, false><<<ROWS, 256, 0, stream>>>(x1, n2w, slotA, flag);
    // 6. ffh = y @ ff1_w + ff1_b
    gemm_k256<2><<<dim3(512 / 64, ROWS / 64), 256, 0, stream>>>(slotA, ff1w, ff1b, nullptr, qkv, 512, flag);
    // 7. g = gelu(gate) * value
    geglu_kernel<<<(ROWS * 256) / 256, 256, 0, stream>>>(qkv, slotA);
    // 8. out = x1 + g @ ff2_w + ff2_b   (store in detected dtype)
    gemm_k256<3><<<dim3(256 / 64, ROWS / 64), 256, 0, stream>>>(slotA, ff2w, ff2b, x1, d_out, 256, flag);
}

// Round 3
// 193.210 us; speedup vs baseline: 2.1639x; 2.1639x over previous
//
#include <hip/hip_runtime.h>
#include <hip/hip_bf16.h>

// ---------------------------------------------------------------------------
// NeighborhoodAttentionBlock: B=2, H=W=64, C=256, nh=4, hd=64, k=7
// R3: bf16 MFMA GEMMs + LDS-tiled neighborhood attention.
// ---------------------------------------------------------------------------

#define ROWS 8192
typedef unsigned int uint32;
typedef unsigned short ushort16;
typedef __attribute__((ext_vector_type(8))) short short8;
typedef __attribute__((ext_vector_type(4))) float floatx4;

__device__ __forceinline__ float bf2f(__hip_bfloat16 b) { return __bfloat162float(b); }
__device__ __forceinline__ float us2f(ushort16 u) {
    return __uint_as_float(((uint32)u) << 16);
}
__device__ __forceinline__ ushort16 f2us(float f) {
    __hip_bfloat16 h = __float2bfloat16(f);
    return *(ushort16*)&h;
}
template <bool F32>
__device__ __forceinline__ float ldany(const void* p, size_t i) {
    return F32 ? ((const float*)p)[i] : bf2f(((const __hip_bfloat16*)p)[i]);
}
__device__ __forceinline__ float ldflag(const void* p, size_t i, int f32) {
    return f32 ? ((const float*)p)[i] : bf2f(((const __hip_bfloat16*)p)[i]);
}

__device__ __forceinline__ void gl_lds16(const void* gptr, void* lptr) {
    __builtin_amdgcn_global_load_lds(
        (const __attribute__((address_space(1))) uint32*)gptr,
        (__attribute__((address_space(3))) uint32*)lptr, 16, 0, 0);
}

// ---------------------------------------------------------------------------
// Dtype detector (unchanged from R2 — verified working).
// ---------------------------------------------------------------------------
__global__ __launch_bounds__(64) void detect_kernel(const ushort16* __restrict__ xu,
                                                    int* __restrict__ flag) {
    const int lane = threadIdx.x;
    const float v = us2f(xu[lane * 62]);
    const float a = fabsf(v);
    const bool sane = (a < 1e4f) && (a > 1e-8f);
    const unsigned long long m = __ballot(sane);
    if (lane == 0) flag[0] = (__popcll(m) < 32) ? 1 : 0;
}

// ---------------------------------------------------------------------------
// Weight convert + transpose: wT[n*256+k] = w[k*N+n] as bf16; biases -> fp32.
// Order: wqkv(196608) | wproj(65536) | ff1w(131072) | ff2w(65536) | biases(1024)
// ---------------------------------------------------------------------------
struct WSrc {
    const void *wqkv, *wproj, *ff1w, *ff2w, *bproj, *ff1b, *ff2b;
};
__global__ __launch_bounds__(256) void cvt_kernel(WSrc s, ushort16* __restrict__ wT,
                                                  float* __restrict__ bF,
                                                  const int* __restrict__ flag) {
    const int i = blockIdx.x * 256 + threadIdx.x;
    const int f32 = flag[0];
    if (i < 458752) {
        const void* src; int N, base;
        if (i < 196608)      { src = s.wqkv; N = 768; base = 0; }
        else if (i < 262144) { src = s.wproj; N = 256; base = 196608; }
        else if (i < 393216) { src = s.ff1w; N = 512; base = 262144; }
        else                 { src = s.ff2w; N = 256; base = 393216; }
        const int loc = i - base, n = loc >> 8, k = loc & 255;
        wT[i] = f2us(ldflag(src, (size_t)k * N + n, f32));
    } else if (i < 458752 + 1024) {
        const int j = i - 458752;
        float v;
        if (j < 256)      v = ldflag(s.bproj, j, f32);
        else if (j < 768) v = ldflag(s.ff1b, j - 256, f32);
        else              v = ldflag(s.ff2b, j - 768, f32);
        bF[j] = v;
    }
}

// ---------------------------------------------------------------------------
// RMSNorm (+ optional RoPE2D) -> bf16 out. One block per row.
// ---------------------------------------------------------------------------
template <bool ROPE, bool IN_EXT>
__global__ __launch_bounds__(256) void rmsnorm_kernel(const void* __restrict__ in,
                                                      const void* __restrict__ w,
                                                      ushort16* __restrict__ out,
                                                      const int* __restrict__ flag) {
    const int f32 = flag[0];
    const int row = blockIdx.x;
    const int c = threadIdx.x;
    const size_t idx = (size_t)row * 256 + c;
    float v = IN_EXT ? ldflag(in, idx, f32) : ((const float*)in)[idx];

    float s = v * v;
    #pragma unroll
    for (int off = 32; off; off >>= 1) s += __shfl_xor(s, off);
    __shared__ float red[4];
    if ((c & 63) == 0) red[c >> 6] = s;
    __syncthreads();
    const float sum = red[0] + red[1] + red[2] + red[3];
    const float r = rsqrtf(sum * (1.0f / 256.0f) + 1e-6f);

    float nv = v * r * ldflag(w, c, f32);

    if (ROPE) {
        const int py = (row >> 6) & 63;
        const int px = row & 63;
        const float pos = (c < 128) ? (float)py : (float)px;
        const int j = (c & 127) >> 1;
        const float inv = expf(-(float)j * (9.210340371976184f / 64.0f));
        const float th = pos * inv;
        const float cs = cosf(th), sn = sinf(th);
        const float partner = __shfl_xor(nv, 1);
        nv = ((c & 1) == 0) ? (nv * cs - partner * sn) : (partner * sn + nv * cs);
    }
    out[idx] = f2us(nv);
}

// ---------------------------------------------------------------------------
// MFMA GEMM: C[M,N] = A[M,256](bf16) @ Bt[N,256]^T(bf16)  (+ epilogue)
// 16x16x32 bf16 MFMA. 4 waves, wave grid WRxWC, per-wave TMxTN tiles.
// EPI: 0 = store bf16
//      1 = + bias + ext residual, store fp32
//      2 = + bias, store bf16
//      3 = + bias + fp32 residual, store ext dtype
// ---------------------------------------------------------------------------
template <int BM, int BN, int WR, int WC, int EPI>
__global__ __launch_bounds__(256) void gemm_mfma(const ushort16* __restrict__ A,
                                                 const ushort16* __restrict__ Bt,
                                                 const float* __restrict__ bias,
                                                 const void* __restrict__ resid,
                                                 void* __restrict__ Cout,
                                                 int N, const int* __restrict__ flag) {
    constexpr int TM = BM / (WR * 16), TN = BN / (WC * 16);
    constexpr int CHA = BM / 16, CHT = (BM + BN) / 16;
    __shared__ ushort16 At[BM * 32];
    __shared__ ushort16 Bs[BN * 32];

    const int f32 = flag[0];
    const int tid = threadIdx.x, lane = tid & 63, wid = tid >> 6;
    const int wr = wid / WC, wc = wid % WC;
    const int m0 = blockIdx.y * BM, n0 = blockIdx.x * BN;
    const int mw = wr * TM * 16, nw = wc * TN * 16;
    const int cr = lane >> 2, cc = (lane & 3) * 8;   // chunk row / col8
    const int l15 = lane & 15, kq = (lane >> 4) * 8;

    floatx4 acc[TM][TN] = {};

    for (int k0 = 0; k0 < 256; k0 += 32) {
        #pragma unroll
        for (int c = 0; c < CHT / 4 + 1; ++c) {
            const int ch = wid + c * 4;
            if (ch < CHT) {
                const ushort16* g;
                ushort16* l;
                if (ch < CHA) {
                    g = A + (size_t)(m0 + ch * 16 + cr) * 256 + k0 + cc;
                    l = At + ch * 512;
                } else {
                    const int c2 = ch - CHA;
                    g = Bt + (size_t)(n0 + c2 * 16 + cr) * 256 + k0 + cc;
                    l = Bs + c2 * 512;
                }
                gl_lds16(g, l);
            }
        }
        __syncthreads();

        short8 af[TM], bf[TN];
        #pragma unroll
        for (int mi = 0; mi < TM; ++mi)
            af[mi] = *(const short8*)&At[(mw + mi * 16 + l15) * 32 + kq];
        #pragma unroll
        for (int nj = 0; nj < TN; ++nj)
            bf[nj] = *(const short8*)&Bs[(nw + nj * 16 + l15) * 32 + kq];
        #pragma unroll
        for (int mi = 0; mi < TM; ++mi)
            #pragma unroll
            for (int nj = 0; nj < TN; ++nj)
                acc[mi][nj] = __builtin_amdgcn_mfma_f32_16x16x32_bf16(af[mi], bf[nj], acc[mi][nj], 0, 0, 0);
        __syncthreads();
    }

    // Epilogue. C/D layout: col = lane&15, row = (lane>>4)*4 + reg.
    const int crow = (lane >> 4) * 4;
    #pragma unroll
    for (int mi = 0; mi < TM; ++mi) {
        #pragma unroll
        for (int nj = 0; nj < TN; ++nj) {
            const int n = n0 + nw + nj * 16 + l15;
            const float bs = (EPI > 0) ? bias[n] : 0.0f;
            #pragma unroll
            for (int r = 0; r < 4; ++r) {
                const int m = m0 + mw + mi * 16 + crow + r;
                const size_t oi = (size_t)m * N + n;
                float v = acc[mi][nj][r] + bs;
                if (EPI == 1) v += ldflag(resid, oi, f32);
                if (EPI == 3) v += ((const float*)resid)[oi];
                if (EPI == 0 || EPI == 2) {
                    ((ushort16*)Cout)[oi] = f2us(v);
                } else if (EPI == 1) {
                    ((float*)Cout)[oi] = v;
                } else {
                    if (f32) ((float*)Cout)[oi] = v;
                    else     ((ushort16*)Cout)[oi] = f2us(v);
                }
            }
        }
    }
}

// ---------------------------------------------------------------------------
// Neighborhood attention. Block = (8x8 pixel tile, head, batch). 256 thr.
// Stage K/V 14x14 halo + Q tile in LDS (bf16, stride 66 for bank spread).
// QK: lane = neighbor (49 of 64). PV: lane = dim, weights via __shfl.
// qkv: bf16 [8192][768] (q at h*64, k at 256+h*64, v at 512+h*64).
// ---------------------------------------------------------------------------
__global__ __launch_bounds__(256) void attn_kernel(const ushort16* __restrict__ qkv,
                                                   ushort16* __restrict__ ao) {
    __shared__ ushort16 Kl[196 * 66];
    __shared__ ushort16 Vl[196 * 66];
    __shared__ ushort16 Ql[64 * 66];

    const int tid = threadIdx.x, lane = tid & 63, wid = tid >> 6;
    const int bid = blockIdx.x;
    const int h = bid & 3;
    const int t = (bid >> 2) & 63;
    const int b = bid >> 8;
    const int ty0 = (t >> 3) * 8, tx0 = (t & 7) * 8;
    const int hby = min(max(ty0 - 3, 0), 50);
    const int hbx = min(max(tx0 - 3, 0), 50);

    // ---- stage: K(1568 chunks) V(1568) Q(512) of 16B each ----
    for (int it = 0; it < 15; ++it) {
        const int idx = it * 256 + tid;
        if (idx < 3648) {
            int p, part, colb, grow;
            ushort16* dst;
            if (idx < 1568) {
                p = idx >> 3; part = idx & 7; colb = 256 + h * 64;
                dst = &Kl[p * 66 + part * 8];
                grow = b * 4096 + (hby + p / 14) * 64 + (hbx + p % 14);
            } else if (idx < 3136) {
                const int q = idx - 1568;
                p = q >> 3; part = q & 7; colb = 512 + h * 64;
                dst = &Vl[p * 66 + part * 8];
                grow = b * 4096 + (hby + p / 14) * 64 + (hbx + p % 14);
            } else {
                const int q = idx - 3136;
                const int pl = q >> 3; part = q & 7; colb = h * 64;
                dst = &Ql[pl * 66 + part * 8];
                grow = b * 4096 + (ty0 + (pl >> 3)) * 64 + (tx0 + (pl & 7));
            }
            const uint4 d = *(const uint4*)&qkv[(size_t)grow * 768 + colb + part * 8];
            uint32* d32 = (uint32*)dst;
            d32[0] = d.x; d32[1] = d.y; d32[2] = d.z; d32[3] = d.w;
        }
    }
    __syncthreads();

    const int nln = lane < 49 ? lane : 48;
    const int nry = nln / 7, nrx = nln % 7;

    for (int pl = wid * 16; pl < wid * 16 + 16; ++pl) {
        const int py = ty0 + (pl >> 3), px = tx0 + (pl & 7);
        const int sy = min(max(py - 3, 0), 57), sx = min(max(px - 3, 0), 57);
        const int oy = sy - hby, ox = sx - hbx;

        // ---- QK: lane = neighbor ----
        const int s = (oy + nry) * 14 + ox + nrx;
        const uint32* kp = (const uint32*)&Kl[s * 66];
        const uint32* qp = (const uint32*)&Ql[pl * 66];
        float acc = 0.0f;
        #pragma unroll
        for (int dd = 0; dd < 32; ++dd) {
            const uint32 kv = kp[dd], qv = qp[dd];
            const float k0 = __uint_as_float(kv << 16);
            const float k1 = __uint_as_float(kv & 0xffff0000u);
            const float q0 = __uint_as_float(qv << 16);
            const float q1 = __uint_as_float(qv & 0xffff0000u);
            acc = fmaf(q1, k1, fmaf(q0, k0, acc));
        }
        const float logit = (lane < 49) ? acc * 0.125f : -1e30f;

        float mx = logit;
        #pragma unroll
        for (int off = 32; off; off >>= 1) mx = fmaxf(mx, __shfl_xor(mx, off));
        float w = __expf(logit - mx);
        float sm = w;
        #pragma unroll
        for (int off = 32; off; off >>= 1) sm += __shfl_xor(sm, off);
        w = w / sm;

        // ---- PV: lane = dim ----
        float o = 0.0f;
        #pragma unroll
        for (int ry = 0; ry < 7; ++ry) {
            const int srow = (oy + ry) * 14 + ox;
            #pragma unroll
            for (int rx = 0; rx < 7; ++rx) {
                const float wn = __shfl(w, ry * 7 + rx);
                const float v = us2f(Vl[(srow + rx) * 66 + lane]);
                o = fmaf(wn, v, o);
            }
        }
        const int pix = b * 4096 + py * 64 + px;
        ao[(size_t)pix * 256 + h * 64 + lane] = f2us(o);
    }
}

// ---------------------------------------------------------------------------
// GEGLU: g = gelu_exact(gate) * value.  ffh bf16 [8192][512] -> g bf16.
// ---------------------------------------------------------------------------
__global__ __launch_bounds__(256) void geglu_kernel(const ushort16* __restrict__ ffh,
                                                    ushort16* __restrict__ g) {
    const int i = blockIdx.x * 256 + threadIdx.x;
    const int row = i >> 8, c = i & 255;
    const float gate = us2f(ffh[(size_t)row * 512 + c]);
    const float val = us2f(ffh[(size_t)row * 512 + 256 + c]);
    const float ge = 0.5f * gate * (1.0f + erff(gate * 0.70710678118654752f));
    g[i] = f2us(ge * val);
}

// ---------------------------------------------------------------------------
extern "C" void kernel_launch(void* const* d_in, const int* in_sizes, int n_in,
                              void* d_out, int out_size, void* d_ws, size_t ws_size,
                              hipStream_t stream) {
    const void* x    = d_in[0];
    const void* n1w  = d_in[1];
    const void* n2w  = d_in[2];
    WSrc ws_src{d_in[3], d_in[4], d_in[6], d_in[8], d_in[5], d_in[7], d_in[9]};

    char* ws = (char*)d_ws;
    int*      flag  = (int*)ws;
    ushort16* wT    = (ushort16*)(ws + 4096);              // 458752 bf16
    float*    bF    = (float*)(ws + 4096 + 458752 * 2);    // 1024 fp32
    ushort16* h     = (ushort16*)(ws + (1 << 20));         // h / y  : 4 MB
    ushort16* qkv   = (ushort16*)(ws + (5 << 20));         // qkv/ffh: 12 MB
    ushort16* ao    = (ushort16*)(ws + (size_t)(17 << 20)); // ao / g : 4 MB
    float*    x1    = (float*)(ws + (size_t)(21 << 20));   // x1     : 8 MB

    ushort16* wqkvT = wT;
    ushort16* wprojT = wT + 196608;
    ushort16* ff1wT = wT + 262144;
    ushort16* ff2wT = wT + 393216;

    detect_kernel<<<1, 64, 0, stream>>>((const ushort16*)x, flag);
    cvt_kernel<<<1796, 256, 0, stream>>>(ws_src, wT, bF, flag);
    // h = bf16(rope2d(rmsnorm(x, n1w)))
    rmsnorm_kernel<true, true><<<ROWS, 256, 0, stream>>>(x, n1w, h, flag);
    // qkv = h @ w_qkv                    (bf16 out)
    gemm_mfma<128, 128, 2, 2, 0><<<dim3(6, 64), 256, 0, stream>>>(h, wqkvT, nullptr, nullptr, qkv, 768, flag);
    // ao = neighborhood_attn(qkv)        (bf16 out)
    attn_kernel<<<512, 256, 0, stream>>>(qkv, ao);
    // x1 = x + ao @ w_proj + b_proj      (fp32 out)
    gemm_mfma<64, 128, 1, 4, 1><<<dim3(2, 128), 256, 0, stream>>>(ao, wprojT, bF, x, x1, 256, flag);
    // y = bf16(rmsnorm(x1, n2w))
    rmsnorm_kernel<false, false><<<ROWS, 256, 0, stream>>>(x1, n2w, h, flag);
    // ffh = y @ ff1_w + ff1_b            (bf16 out)
    gemm_mfma<128, 128, 2, 2, 2><<<dim3(4, 64), 256, 0, stream>>>(h, ff1wT, bF + 256, nullptr, qkv, 512, flag);
    // g = gelu(gate) * value             (bf16 out)
    geglu_kernel<<<ROWS, 256, 0, stream>>>(qkv, ao);
    // out = x1 + g @ ff2_w + ff2_b       (ext dtype out)
    gemm_mfma<64, 128, 1, 4, 3><<<dim3(2, 128), 256, 0, stream>>>(ao, ff2wT, bF + 768, x1, d_out, 256, flag);
}

// Round 4
// 163.245 us; speedup vs baseline: 2.5611x; 1.1836x over previous
//
#include <hip/hip_runtime.h>
#include <hip/hip_bf16.h>

// ---------------------------------------------------------------------------
// NeighborhoodAttentionBlock: B=2, H=W=64, C=256, nh=4, hd=64, k=7
// R4: attention via masked dense MFMA over the 14x14 halo.
// ---------------------------------------------------------------------------

#define ROWS 8192
typedef unsigned int uint32;
typedef unsigned short ushort16;
typedef __attribute__((ext_vector_type(8))) short short8;
typedef __attribute__((ext_vector_type(4))) float floatx4;

__device__ __forceinline__ float bf2f(__hip_bfloat16 b) { return __bfloat162float(b); }
__device__ __forceinline__ float us2f(ushort16 u) {
    return __uint_as_float(((uint32)u) << 16);
}
__device__ __forceinline__ ushort16 f2us(float f) {
    __hip_bfloat16 h = __float2bfloat16(f);
    return *(ushort16*)&h;
}
__device__ __forceinline__ float ldflag(const void* p, size_t i, int f32) {
    return f32 ? ((const float*)p)[i] : bf2f(((const __hip_bfloat16*)p)[i]);
}

__device__ __forceinline__ void gl_lds16(const void* gptr, void* lptr) {
    __builtin_amdgcn_global_load_lds(
        (const __attribute__((address_space(1))) uint32*)gptr,
        (__attribute__((address_space(3))) uint32*)lptr, 16, 0, 0);
}

// ---------------------------------------------------------------------------
// Dtype detector (verified working).
// ---------------------------------------------------------------------------
__global__ __launch_bounds__(64) void detect_kernel(const ushort16* __restrict__ xu,
                                                    int* __restrict__ flag) {
    const int lane = threadIdx.x;
    const float v = us2f(xu[lane * 62]);
    const float a = fabsf(v);
    const bool sane = (a < 1e4f) && (a > 1e-8f);
    const unsigned long long m = __ballot(sane);
    if (lane == 0) flag[0] = (__popcll(m) < 32) ? 1 : 0;
}

// ---------------------------------------------------------------------------
// Weight convert + transpose (verified working).
// ---------------------------------------------------------------------------
struct WSrc {
    const void *wqkv, *wproj, *ff1w, *ff2w, *bproj, *ff1b, *ff2b;
};
__global__ __launch_bounds__(256) void cvt_kernel(WSrc s, ushort16* __restrict__ wT,
                                                  float* __restrict__ bF,
                                                  const int* __restrict__ flag) {
    const int i = blockIdx.x * 256 + threadIdx.x;
    const int f32 = flag[0];
    if (i < 458752) {
        const void* src; int N, base;
        if (i < 196608)      { src = s.wqkv; N = 768; base = 0; }
        else if (i < 262144) { src = s.wproj; N = 256; base = 196608; }
        else if (i < 393216) { src = s.ff1w; N = 512; base = 262144; }
        else                 { src = s.ff2w; N = 256; base = 393216; }
        const int loc = i - base, n = loc >> 8, k = loc & 255;
        wT[i] = f2us(ldflag(src, (size_t)k * N + n, f32));
    } else if (i < 458752 + 1024) {
        const int j = i - 458752;
        float v;
        if (j < 256)      v = ldflag(s.bproj, j, f32);
        else if (j < 768) v = ldflag(s.ff1b, j - 256, f32);
        else              v = ldflag(s.ff2b, j - 768, f32);
        bF[j] = v;
    }
}

// ---------------------------------------------------------------------------
// RMSNorm (+ optional RoPE2D) -> bf16 out. One block per row.
// ---------------------------------------------------------------------------
template <bool ROPE, bool IN_EXT>
__global__ __launch_bounds__(256) void rmsnorm_kernel(const void* __restrict__ in,
                                                      const void* __restrict__ w,
                                                      ushort16* __restrict__ out,
                                                      const int* __restrict__ flag) {
    const int f32 = flag[0];
    const int row = blockIdx.x;
    const int c = threadIdx.x;
    const size_t idx = (size_t)row * 256 + c;
    float v = IN_EXT ? ldflag(in, idx, f32) : ((const float*)in)[idx];

    float s = v * v;
    #pragma unroll
    for (int off = 32; off; off >>= 1) s += __shfl_xor(s, off);
    __shared__ float red[4];
    if ((c & 63) == 0) red[c >> 6] = s;
    __syncthreads();
    const float sum = red[0] + red[1] + red[2] + red[3];
    const float r = rsqrtf(sum * (1.0f / 256.0f) + 1e-6f);

    float nv = v * r * ldflag(w, c, f32);

    if (ROPE) {
        const int py = (row >> 6) & 63;
        const int px = row & 63;
        const float pos = (c < 128) ? (float)py : (float)px;
        const int j = (c & 127) >> 1;
        const float inv = expf(-(float)j * (9.210340371976184f / 64.0f));
        const float th = pos * inv;
        const float cs = cosf(th), sn = sinf(th);
        const float partner = __shfl_xor(nv, 1);
        nv = ((c & 1) == 0) ? (nv * cs - partner * sn) : (partner * sn + nv * cs);
    }
    out[idx] = f2us(nv);
}

// ---------------------------------------------------------------------------
// MFMA GEMM (verified working): C[M,N] = A[M,256](bf16) @ Bt[N,256]^T (+ epi)
// ---------------------------------------------------------------------------
template <int BM, int BN, int WR, int WC, int EPI>
__global__ __launch_bounds__(256) void gemm_mfma(const ushort16* __restrict__ A,
                                                 const ushort16* __restrict__ Bt,
                                                 const float* __restrict__ bias,
                                                 const void* __restrict__ resid,
                                                 void* __restrict__ Cout,
                                                 int N, const int* __restrict__ flag) {
    constexpr int TM = BM / (WR * 16), TN = BN / (WC * 16);
    constexpr int CHA = BM / 16, CHT = (BM + BN) / 16;
    __shared__ ushort16 At[BM * 32];
    __shared__ ushort16 Bs[BN * 32];

    const int f32 = flag[0];
    const int tid = threadIdx.x, lane = tid & 63, wid = tid >> 6;
    const int wr = wid / WC, wc = wid % WC;
    const int m0 = blockIdx.y * BM, n0 = blockIdx.x * BN;
    const int mw = wr * TM * 16, nw = wc * TN * 16;
    const int cr = lane >> 2, cc = (lane & 3) * 8;
    const int l15 = lane & 15, kq = (lane >> 4) * 8;

    floatx4 acc[TM][TN] = {};

    for (int k0 = 0; k0 < 256; k0 += 32) {
        #pragma unroll
        for (int c = 0; c < CHT / 4 + 1; ++c) {
            const int ch = wid + c * 4;
            if (ch < CHT) {
                const ushort16* g;
                ushort16* l;
                if (ch < CHA) {
                    g = A + (size_t)(m0 + ch * 16 + cr) * 256 + k0 + cc;
                    l = At + ch * 512;
                } else {
                    const int c2 = ch - CHA;
                    g = Bt + (size_t)(n0 + c2 * 16 + cr) * 256 + k0 + cc;
                    l = Bs + c2 * 512;
                }
                gl_lds16(g, l);
            }
        }
        __syncthreads();

        short8 af[TM], bf[TN];
        #pragma unroll
        for (int mi = 0; mi < TM; ++mi)
            af[mi] = *(const short8*)&At[(mw + mi * 16 + l15) * 32 + kq];
        #pragma unroll
        for (int nj = 0; nj < TN; ++nj)
            bf[nj] = *(const short8*)&Bs[(nw + nj * 16 + l15) * 32 + kq];
        #pragma unroll
        for (int mi = 0; mi < TM; ++mi)
            #pragma unroll
            for (int nj = 0; nj < TN; ++nj)
                acc[mi][nj] = __builtin_amdgcn_mfma_f32_16x16x32_bf16(af[mi], bf[nj], acc[mi][nj], 0, 0, 0);
        __syncthreads();
    }

    const int crow = (lane >> 4) * 4;
    #pragma unroll
    for (int mi = 0; mi < TM; ++mi) {
        #pragma unroll
        for (int nj = 0; nj < TN; ++nj) {
            const int n = n0 + nw + nj * 16 + l15;
            const float bs = (EPI > 0) ? bias[n] : 0.0f;
            #pragma unroll
            for (int r = 0; r < 4; ++r) {
                const int m = m0 + mw + mi * 16 + crow + r;
                const size_t oi = (size_t)m * N + n;
                float v = acc[mi][nj][r] + bs;
                if (EPI == 1) v += ldflag(resid, oi, f32);
                if (EPI == 3) v += ((const float*)resid)[oi];
                if (EPI == 0 || EPI == 2) {
                    ((ushort16*)Cout)[oi] = f2us(v);
                } else if (EPI == 1) {
                    ((float*)Cout)[oi] = v;
                } else {
                    if (f32) ((float*)Cout)[oi] = v;
                    else     ((ushort16*)Cout)[oi] = f2us(v);
                }
            }
        }
    }
}

// ---------------------------------------------------------------------------
// Neighborhood attention via masked dense MFMA.
// Block = (8x8 tile, head, batch). 4 waves; wave w owns queries 16w..16w+15.
// S = Q(64x64) @ K_halo^T(208x64, 196 real) ; mask |dy|>3 or |dx|>3 -> -1e30;
// softmax across l15 lanes; P -> LDS (A-layout, bf16); O = P @ V^T via MFMA.
// LDS: KS 2 planes [196][32us] | VT [64][224us] (cols 196.. zero) |
//      PL [64][208us]+16 pad.  Over-reads land in allocated LDS and are
//      either masked (S) or multiplied by VT zeros (PV chunk 6).
// ---------------------------------------------------------------------------
__global__ __launch_bounds__(256) void attn_kernel(const ushort16* __restrict__ qkv,
                                                   ushort16* __restrict__ ao) {
    __shared__ ushort16 smem[40208];
    ushort16* const KS = smem;            // 12544 us
    ushort16* const VT = smem + 12544;    // 14336 us
    ushort16* const PL = smem + 26880;    // 13328 us

    const int tid = threadIdx.x, lane = tid & 63, wid = tid >> 6;
    const int l15 = lane & 15, kq8 = (lane >> 4) * 8;
    const int bid = blockIdx.x;
    const int h = bid & 3;
    const int t = (bid >> 2) & 63;
    const int b = bid >> 8;
    const int ty0 = (t >> 3) * 8, tx0 = (t & 7) * 8;
    const int hby = min(max(ty0 - 3, 0), 50);
    const int hbx = min(max(tx0 - 3, 0), 50);
    const int hcol = h * 64;

    // Q fragments (A-layout) straight from global: query = wid*16 + l15
    const int qpl = wid * 16 + l15;
    const int qpy = ty0 + (qpl >> 3), qpx = tx0 + (qpl & 7);
    const size_t qoff = (size_t)(b * 4096 + qpy * 64 + qpx) * 768 + hcol + kq8;
    const short8 af0 = *(const short8*)&qkv[qoff];
    const short8 af1 = *(const short8*)&qkv[qoff + 32];

    // ---- stage K (2 k-planes) + V (transposed) ----
    for (int it = tid; it < 3136; it += 256) {
        const bool isK = it < 1568;
        const int task = isK ? it : it - 1568;
        const int key = task >> 3, oct = task & 7;
        const int pix = b * 4096 + (hby + key / 14) * 64 + hbx + key % 14;
        const uint4 d = *(const uint4*)&qkv[(size_t)pix * 768 + (isK ? 256 : 512) + hcol + oct * 8];
        if (isK) {
            uint32* dst = (uint32*)&KS[(oct >> 2) * 6272 + key * 32 + (oct & 3) * 8];
            dst[0] = d.x; dst[1] = d.y; dst[2] = d.z; dst[3] = d.w;
        } else {
            const ushort16* s8 = (const ushort16*)&d;
            #pragma unroll
            for (int j = 0; j < 8; ++j) VT[(oct * 8 + j) * 224 + key] = s8[j];
        }
    }
    for (int it = tid; it < 1792; it += 256)          // zero VT cols 196..223
        VT[(it / 28) * 224 + 196 + (it % 28)] = 0;
    __syncthreads();

    // ---- QK^T ----
    floatx4 acc[13];
    #pragma unroll
    for (int nt = 0; nt < 13; ++nt) {
        const int krow = (nt * 16 + l15) * 32 + kq8;
        const short8 bf0 = *(const short8*)&KS[krow];
        const short8 bf1 = *(const short8*)&KS[6272 + krow];
        floatx4 a = {0.0f, 0.0f, 0.0f, 0.0f};
        a = __builtin_amdgcn_mfma_f32_16x16x32_bf16(af0, bf0, a, 0, 0, 0);
        a = __builtin_amdgcn_mfma_f32_16x16x32_bf16(af1, bf1, a, 0, 0, 0);
        acc[nt] = a;
    }

    int kyA[13], kxA[13];
    #pragma unroll
    for (int nt = 0; nt < 13; ++nt) {
        const int kidx = nt * 16 + l15;
        kyA[nt] = hby + kidx / 14;
        kxA[nt] = hbx + kidx % 14;
    }

    // ---- mask + softmax (per C-layout row) + P write ----
    const int crow = (lane >> 4) * 4;
    float rs[4];
    #pragma unroll
    for (int r = 0; r < 4; ++r) {
        const int pl = wid * 16 + crow + r;
        const int py = ty0 + (pl >> 3), px = tx0 + (pl & 7);
        const int sy = min(max(py - 3, 0), 57), sx = min(max(px - 3, 0), 57);
        float lv[13];
        float mx = -1e30f;
        #pragma unroll
        for (int nt = 0; nt < 13; ++nt) {
            const int kidx = nt * 16 + l15;
            const bool valid = (kidx < 196) &&
                               ((unsigned)(kyA[nt] - sy) < 7u) &&
                               ((unsigned)(kxA[nt] - sx) < 7u);
            lv[nt] = valid ? acc[nt][r] * 0.125f : -1e30f;
            mx = fmaxf(mx, lv[nt]);
        }
        #pragma unroll
        for (int off = 1; off < 16; off <<= 1) mx = fmaxf(mx, __shfl_xor(mx, off));
        float sme = 0.0f;
        #pragma unroll
        for (int nt = 0; nt < 13; ++nt) {
            const float e = exp2f((lv[nt] - mx) * 1.4426950408889634f);
            lv[nt] = e;
            sme += e;
        }
        #pragma unroll
        for (int off = 1; off < 16; off <<= 1) sme += __shfl_xor(sme, off);
        rs[r] = 1.0f / sme;
        #pragma unroll
        for (int nt = 0; nt < 13; ++nt)
            PL[pl * 208 + nt * 16 + l15] = f2us(lv[nt]);
    }
    __syncthreads();

    // ---- PV ----
    floatx4 oacc[4] = {};
    #pragma unroll
    for (int kc = 0; kc < 7; ++kc) {
        const short8 af = *(const short8*)&PL[(wid * 16 + l15) * 208 + kc * 32 + kq8];
        #pragma unroll
        for (int nd = 0; nd < 4; ++nd) {
            const short8 bf = *(const short8*)&VT[(nd * 16 + l15) * 224 + kc * 32 + kq8];
            oacc[nd] = __builtin_amdgcn_mfma_f32_16x16x32_bf16(af, bf, oacc[nd], 0, 0, 0);
        }
    }
    #pragma unroll
    for (int r = 0; r < 4; ++r) {
        const int pl = wid * 16 + crow + r;
        const int py = ty0 + (pl >> 3), px = tx0 + (pl & 7);
        const size_t o = (size_t)(b * 4096 + py * 64 + px) * 256 + hcol;
        #pragma unroll
        for (int nd = 0; nd < 4; ++nd)
            ao[o + nd * 16 + l15] = f2us(oacc[nd][r] * rs[r]);
    }
}

// ---------------------------------------------------------------------------
// GEGLU: g = gelu_exact(gate) * value.
// ---------------------------------------------------------------------------
__global__ __launch_bounds__(256) void geglu_kernel(const ushort16* __restrict__ ffh,
                                                    ushort16* __restrict__ g) {
    const int i = blockIdx.x * 256 + threadIdx.x;
    const int row = i >> 8, c = i & 255;
    const float gate = us2f(ffh[(size_t)row * 512 + c]);
    const float val = us2f(ffh[(size_t)row * 512 + 256 + c]);
    const float ge = 0.5f * gate * (1.0f + erff(gate * 0.70710678118654752f));
    g[i] = f2us(ge * val);
}

// ---------------------------------------------------------------------------
extern "C" void kernel_launch(void* const* d_in, const int* in_sizes, int n_in,
                              void* d_out, int out_size, void* d_ws, size_t ws_size,
                              hipStream_t stream) {
    const void* x    = d_in[0];
    const void* n1w  = d_in[1];
    const void* n2w  = d_in[2];
    WSrc ws_src{d_in[3], d_in[4], d_in[6], d_in[8], d_in[5], d_in[7], d_in[9]};

    char* ws = (char*)d_ws;
    int*      flag  = (int*)ws;
    ushort16* wT    = (ushort16*)(ws + 4096);
    float*    bF    = (float*)(ws + 4096 + 458752 * 2);
    ushort16* h     = (ushort16*)(ws + (1 << 20));
    ushort16* qkv   = (ushort16*)(ws + (5 << 20));
    ushort16* ao    = (ushort16*)(ws + (size_t)(17 << 20));
    float*    x1    = (float*)(ws + (size_t)(21 << 20));

    ushort16* wqkvT = wT;
    ushort16* wprojT = wT + 196608;
    ushort16* ff1wT = wT + 262144;
    ushort16* ff2wT = wT + 393216;

    detect_kernel<<<1, 64, 0, stream>>>((const ushort16*)x, flag);
    cvt_kernel<<<1796, 256, 0, stream>>>(ws_src, wT, bF, flag);
    rmsnorm_kernel<true, true><<<ROWS, 256, 0, stream>>>(x, n1w, h, flag);
    gemm_mfma<128, 128, 2, 2, 0><<<dim3(6, 64), 256, 0, stream>>>(h, wqkvT, nullptr, nullptr, qkv, 768, flag);
    attn_kernel<<<512, 256, 0, stream>>>(qkv, ao);
    gemm_mfma<64, 128, 1, 4, 1><<<dim3(2, 128), 256, 0, stream>>>(ao, wprojT, bF, x, x1, 256, flag);
    rmsnorm_kernel<false, false><<<ROWS, 256, 0, stream>>>(x1, n2w, h, flag);
    gemm_mfma<128, 128, 2, 2, 2><<<dim3(4, 64), 256, 0, stream>>>(h, ff1wT, bF + 256, nullptr, qkv, 512, flag);
    geglu_kernel<<<ROWS, 256, 0, stream>>>(qkv, ao);
    gemm_mfma<64, 128, 1, 4, 3><<<dim3(2, 128), 256, 0, stream>>>(ao, ff2wT, bF + 768, x1, d_out, 256, flag);
}

// Round 5
// 153.594 us; speedup vs baseline: 2.7221x; 1.0628x over previous
//
#include <hip/hip_runtime.h>
#include <hip/hip_bf16.h>

// ---------------------------------------------------------------------------
// NeighborhoodAttentionBlock: B=2, H=W=64, C=256, nh=4, hd=64, k=7
// R5: coalesced weight transpose, fused proj+rmsnorm2, fused ff1+GEGLU,
//     vectorized rmsnorm1. Attn kernel = verified R4 version.
// ---------------------------------------------------------------------------

#define ROWS 8192
typedef unsigned int uint32;
typedef unsigned short ushort16;
typedef __attribute__((ext_vector_type(8))) short short8;
typedef __attribute__((ext_vector_type(4))) float floatx4;

__device__ __forceinline__ float bf2f(__hip_bfloat16 b) { return __bfloat162float(b); }
__device__ __forceinline__ float us2f(ushort16 u) {
    return __uint_as_float(((uint32)u) << 16);
}
__device__ __forceinline__ ushort16 f2us(float f) {
    __hip_bfloat16 h = __float2bfloat16(f);
    return *(ushort16*)&h;
}
__device__ __forceinline__ float ldflag(const void* p, size_t i, int f32) {
    return f32 ? ((const float*)p)[i] : bf2f(((const __hip_bfloat16*)p)[i]);
}

__device__ __forceinline__ void gl_lds16(const void* gptr, void* lptr) {
    __builtin_amdgcn_global_load_lds(
        (const __attribute__((address_space(1))) uint32*)gptr,
        (__attribute__((address_space(3))) uint32*)lptr, 16, 0, 0);
}

// ---------------------------------------------------------------------------
// Dtype detector (verified).
// ---------------------------------------------------------------------------
__global__ __launch_bounds__(64) void detect_kernel(const ushort16* __restrict__ xu,
                                                    int* __restrict__ flag) {
    const int lane = threadIdx.x;
    const float v = us2f(xu[lane * 62]);
    const float a = fabsf(v);
    const bool sane = (a < 1e4f) && (a > 1e-8f);
    const unsigned long long m = __ballot(sane);
    if (lane == 0) flag[0] = (__popcll(m) < 32) ? 1 : 0;
}

// ---------------------------------------------------------------------------
// Weight convert + transpose, tiled & coalesced. 112 tile blocks + 1 bias.
// wT[n*256+k] = w[k*N+n] as bf16; biases -> fp32.
// ---------------------------------------------------------------------------
struct WSrc {
    const void *wqkv, *wproj, *ff1w, *ff2w, *bproj, *ff1b, *ff2b;
};
__global__ __launch_bounds__(256) void cvt_kernel(WSrc s, ushort16* __restrict__ wT,
                                                  float* __restrict__ bF,
                                                  const int* __restrict__ flag) {
    const int f32 = flag[0];
    const int bid = blockIdx.x, tid = threadIdx.x;
    if (bid == 112) {
        #pragma unroll
        for (int it = 0; it < 4; ++it) {
            const int j = it * 256 + tid;
            float v;
            if (j < 256)      v = ldflag(s.bproj, j, f32);
            else if (j < 768) v = ldflag(s.ff1b, j - 256, f32);
            else              v = ldflag(s.ff2b, j - 768, f32);
            bF[j] = v;
        }
        return;
    }
    const void* src; int N, kt, nt, base;
    if (bid < 48)      { src = s.wqkv;  N = 768; kt = bid / 12;      nt = bid % 12;      base = 0; }
    else if (bid < 64) { const int l = bid - 48; src = s.wproj; N = 256; kt = l / 4; nt = l % 4; base = 196608; }
    else if (bid < 96) { const int l = bid - 64; src = s.ff1w;  N = 512; kt = l / 8; nt = l % 8; base = 262144; }
    else               { const int l = bid - 96; src = s.ff2w;  N = 256; kt = l / 4; nt = l % 4; base = 393216; }

    __shared__ ushort16 T[64][65];
    const int r0 = tid >> 6, c = tid & 63;
    #pragma unroll
    for (int j = 0; j < 16; ++j) {
        const int r = j * 4 + r0;
        T[r][c] = f2us(ldflag(src, (size_t)(kt * 64 + r) * N + nt * 64 + c, f32));
    }
    __syncthreads();
    const int n = tid >> 2, kg = tid & 3;
    #pragma unroll
    for (int j = 0; j < 16; ++j) {
        const int k = kg * 16 + j;
        wT[base + (size_t)(nt * 64 + n) * 256 + kt * 64 + k] = T[k][n];
    }
}

// ---------------------------------------------------------------------------
// RMSNorm1 + RoPE2D -> bf16. One wave per row, 4 elems/lane (pairs intra-lane).
// ---------------------------------------------------------------------------
__global__ __launch_bounds__(256) void rms1_kernel(const void* __restrict__ in,
                                                   const void* __restrict__ w,
                                                   ushort16* __restrict__ out,
                                                   const int* __restrict__ flag) {
    const int f32 = flag[0];
    const int wid = threadIdx.x >> 6, lane = threadIdx.x & 63;
    const int row = blockIdx.x * 4 + wid;
    const int c0 = lane * 4;
    const size_t base = (size_t)row * 256 + c0;

    float v[4];
    if (f32) {
        const float4 d = *(const float4*)((const float*)in + base);
        v[0] = d.x; v[1] = d.y; v[2] = d.z; v[3] = d.w;
    } else {
        const ushort4 d = *(const ushort4*)((const ushort16*)in + base);
        v[0] = us2f(d.x); v[1] = us2f(d.y); v[2] = us2f(d.z); v[3] = us2f(d.w);
    }

    float sq = v[0] * v[0] + v[1] * v[1] + v[2] * v[2] + v[3] * v[3];
    #pragma unroll
    for (int off = 32; off; off >>= 1) sq += __shfl_xor(sq, off);
    const float rr = rsqrtf(sq * (1.0f / 256.0f) + 1e-6f);

    float nv[4];
    #pragma unroll
    for (int i = 0; i < 4; ++i) nv[i] = v[i] * rr * ldflag(w, c0 + i, f32);

    // RoPE: pairs (c0,c0+1) and (c0+2,c0+3); c0<128 -> y half, else x half.
    const int py = (row >> 6) & 63, px = row & 63;
    const float pos = (c0 < 128) ? (float)py : (float)px;
    const int j0 = (c0 & 127) >> 1;
    #pragma unroll
    for (int p = 0; p < 2; ++p) {
        const float inv = expf(-(float)(j0 + p) * (9.210340371976184f / 64.0f));
        const float th = pos * inv;
        const float cs = cosf(th), sn = sinf(th);
        const float a = nv[p * 2], b = nv[p * 2 + 1];
        nv[p * 2]     = a * cs - b * sn;
        nv[p * 2 + 1] = a * sn + b * cs;
    }
    ushort4 o;
    o.x = f2us(nv[0]); o.y = f2us(nv[1]); o.z = f2us(nv[2]); o.w = f2us(nv[3]);
    *(ushort4*)(out + base) = o;
}

// ---------------------------------------------------------------------------
// MFMA GEMM (verified): C[M,N] = A[M,256](bf16) @ Bt[N,256]^T (+ epi)
// EPI: 0 = store bf16;  3 = + bias + fp32 residual, store ext dtype
// ---------------------------------------------------------------------------
template <int BM, int BN, int WR, int WC, int EPI>
__global__ __launch_bounds__(256) void gemm_mfma(const ushort16* __restrict__ A,
                                                 const ushort16* __restrict__ Bt,
                                                 const float* __restrict__ bias,
                                                 const void* __restrict__ resid,
                                                 void* __restrict__ Cout,
                                                 int N, const int* __restrict__ flag) {
    constexpr int TM = BM / (WR * 16), TN = BN / (WC * 16);
    constexpr int CHA = BM / 16, CHT = (BM + BN) / 16;
    __shared__ ushort16 At[BM * 32];
    __shared__ ushort16 Bs[BN * 32];

    const int f32 = flag[0];
    const int tid = threadIdx.x, lane = tid & 63, wid = tid >> 6;
    const int wr = wid / WC, wc = wid % WC;
    const int m0 = blockIdx.y * BM, n0 = blockIdx.x * BN;
    const int mw = wr * TM * 16, nw = wc * TN * 16;
    const int cr = lane >> 2, cc = (lane & 3) * 8;
    const int l15 = lane & 15, kq = (lane >> 4) * 8;

    floatx4 acc[TM][TN] = {};

    for (int k0 = 0; k0 < 256; k0 += 32) {
        #pragma unroll
        for (int c = 0; c < CHT / 4 + 1; ++c) {
            const int ch = wid + c * 4;
            if (ch < CHT) {
                const ushort16* g;
                ushort16* l;
                if (ch < CHA) {
                    g = A + (size_t)(m0 + ch * 16 + cr) * 256 + k0 + cc;
                    l = At + ch * 512;
                } else {
                    const int c2 = ch - CHA;
                    g = Bt + (size_t)(n0 + c2 * 16 + cr) * 256 + k0 + cc;
                    l = Bs + c2 * 512;
                }
                gl_lds16(g, l);
            }
        }
        __syncthreads();

        short8 af[TM], bf[TN];
        #pragma unroll
        for (int mi = 0; mi < TM; ++mi)
            af[mi] = *(const short8*)&At[(mw + mi * 16 + l15) * 32 + kq];
        #pragma unroll
        for (int nj = 0; nj < TN; ++nj)
            bf[nj] = *(const short8*)&Bs[(nw + nj * 16 + l15) * 32 + kq];
        #pragma unroll
        for (int mi = 0; mi < TM; ++mi)
            #pragma unroll
            for (int nj = 0; nj < TN; ++nj)
                acc[mi][nj] = __builtin_amdgcn_mfma_f32_16x16x32_bf16(af[mi], bf[nj], acc[mi][nj], 0, 0, 0);
        __syncthreads();
    }

    const int crow = (lane >> 4) * 4;
    #pragma unroll
    for (int mi = 0; mi < TM; ++mi) {
        #pragma unroll
        for (int nj = 0; nj < TN; ++nj) {
            const int n = n0 + nw + nj * 16 + l15;
            const float bs = (EPI > 0) ? bias[n] : 0.0f;
            #pragma unroll
            for (int r = 0; r < 4; ++r) {
                const int m = m0 + mw + mi * 16 + crow + r;
                const size_t oi = (size_t)m * N + n;
                float v = acc[mi][nj][r] + bs;
                if (EPI == 3) v += ((const float*)resid)[oi];
                if (EPI == 0) {
                    ((ushort16*)Cout)[oi] = f2us(v);
                } else {
                    if (f32) ((float*)Cout)[oi] = v;
                    else     ((ushort16*)Cout)[oi] = f2us(v);
                }
            }
        }
    }
}

// ---------------------------------------------------------------------------
// Fused proj GEMM + residual + RMSNorm2.
// BM=32, BN=256 (full row). x1 = x + ao@wproj + bproj (fp32 out);
// y = rmsnorm(x1, n2w) (bf16 out). Grid: 256 blocks (M/32).
// ---------------------------------------------------------------------------
__global__ __launch_bounds__(256) void gemm_proj_rms(const ushort16* __restrict__ A,
                                                     const ushort16* __restrict__ Bt,
                                                     const float* __restrict__ bias,
                                                     const void* __restrict__ xres,
                                                     const void* __restrict__ n2w,
                                                     float* __restrict__ x1,
                                                     ushort16* __restrict__ y,
                                                     const int* __restrict__ flag) {
    constexpr int TM = 2, TN = 4;        // WR=1, WC=4
    __shared__ ushort16 At[32 * 32];
    __shared__ ushort16 Bs[256 * 32];
    __shared__ float red[4][32];

    const int f32 = flag[0];
    const int tid = threadIdx.x, lane = tid & 63, wid = tid >> 6;
    const int m0 = blockIdx.x * 32;
    const int nw = wid * 64;
    const int cr = lane >> 2, cc = (lane & 3) * 8;
    const int l15 = lane & 15, kq = (lane >> 4) * 8;

    floatx4 acc[TM][TN] = {};

    for (int k0 = 0; k0 < 256; k0 += 32) {
        #pragma unroll
        for (int c = 0; c < 5; ++c) {
            const int ch = wid + c * 4;
            if (ch < 18) {
                const ushort16* g;
                ushort16* l;
                if (ch < 2) {
                    g = A + (size_t)(m0 + ch * 16 + cr) * 256 + k0 + cc;
                    l = At + ch * 512;
                } else {
                    const int c2 = ch - 2;
                    g = Bt + (size_t)(c2 * 16 + cr) * 256 + k0 + cc;
                    l = Bs + c2 * 512;
                }
                gl_lds16(g, l);
            }
        }
        __syncthreads();

        short8 af[TM], bf[TN];
        #pragma unroll
        for (int mi = 0; mi < TM; ++mi)
            af[mi] = *(const short8*)&At[(mi * 16 + l15) * 32 + kq];
        #pragma unroll
        for (int nj = 0; nj < TN; ++nj)
            bf[nj] = *(const short8*)&Bs[(nw + nj * 16 + l15) * 32 + kq];
        #pragma unroll
        for (int mi = 0; mi < TM; ++mi)
            #pragma unroll
            for (int nj = 0; nj < TN; ++nj)
                acc[mi][nj] = __builtin_amdgcn_mfma_f32_16x16x32_bf16(af[mi], bf[nj], acc[mi][nj], 0, 0, 0);
        __syncthreads();
    }

    const int crow = (lane >> 4) * 4;
    float w2[TN], bsv[TN];
    #pragma unroll
    for (int nj = 0; nj < TN; ++nj) {
        const int n = nw + nj * 16 + l15;
        w2[nj] = ldflag(n2w, n, f32);
        bsv[nj] = bias[n];
    }

    float ps[TM][4] = {};
    #pragma unroll
    for (int mi = 0; mi < TM; ++mi)
        #pragma unroll
        for (int nj = 0; nj < TN; ++nj)
            #pragma unroll
            for (int r = 0; r < 4; ++r) {
                const int m = m0 + mi * 16 + crow + r;
                const int n = nw + nj * 16 + l15;
                float v = acc[mi][nj][r] + bsv[nj] + ldflag(xres, (size_t)m * 256 + n, f32);
                acc[mi][nj][r] = v;
                ps[mi][r] += v * v;
            }
    #pragma unroll
    for (int off = 1; off < 16; off <<= 1)
        #pragma unroll
        for (int mi = 0; mi < TM; ++mi)
            #pragma unroll
            for (int r = 0; r < 4; ++r) ps[mi][r] += __shfl_xor(ps[mi][r], off);
    if (l15 == 0)
        #pragma unroll
        for (int mi = 0; mi < TM; ++mi)
            #pragma unroll
            for (int r = 0; r < 4; ++r) red[wid][mi * 16 + crow + r] = ps[mi][r];
    __syncthreads();

    float rr[TM][4];
    #pragma unroll
    for (int mi = 0; mi < TM; ++mi)
        #pragma unroll
        for (int r = 0; r < 4; ++r) {
            const int row = mi * 16 + crow + r;
            const float s = red[0][row] + red[1][row] + red[2][row] + red[3][row];
            rr[mi][r] = rsqrtf(s * (1.0f / 256.0f) + 1e-6f);
        }
    #pragma unroll
    for (int mi = 0; mi < TM; ++mi)
        #pragma unroll
        for (int nj = 0; nj < TN; ++nj)
            #pragma unroll
            for (int r = 0; r < 4; ++r) {
                const int m = m0 + mi * 16 + crow + r;
                const int n = nw + nj * 16 + l15;
                const size_t oi = (size_t)m * 256 + n;
                const float v = acc[mi][nj][r];
                x1[oi] = v;
                y[oi] = f2us(v * rr[mi][r] * w2[nj]);
            }
}

// ---------------------------------------------------------------------------
// Fused FF1 GEMM + GEGLU. Block: 128 rows x 64 g-cols; computes matching
// gate (n) and value (n+256) tiles, writes g = gelu(gate)*value (bf16).
// Grid dim3(4, 64). WR=4, WC=1: TM=2 per wave, TN=4.
// ---------------------------------------------------------------------------
__global__ __launch_bounds__(256) void gemm_ff1_geglu(const ushort16* __restrict__ A,
                                                      const ushort16* __restrict__ Bt,
                                                      const float* __restrict__ bF,
                                                      ushort16* __restrict__ g,
                                                      const int* __restrict__ flag) {
    constexpr int TM = 2, TN = 4;
    __shared__ ushort16 At[128 * 32];
    __shared__ ushort16 Bg[64 * 32];
    __shared__ ushort16 Bv[64 * 32];

    const int tid = threadIdx.x, lane = tid & 63, wid = tid >> 6;
    const int m0 = blockIdx.y * 128, ng0 = blockIdx.x * 64;
    const int mw = wid * 32;
    const int cr = lane >> 2, cc = (lane & 3) * 8;
    const int l15 = lane & 15, kq = (lane >> 4) * 8;

    floatx4 accg[TM][TN] = {}, accv[TM][TN] = {};

    for (int k0 = 0; k0 < 256; k0 += 32) {
        #pragma unroll
        for (int c = 0; c < 4; ++c) {
            const int ch = wid + c * 4;   // 0..15
            const ushort16* gp;
            ushort16* l;
            if (ch < 8) {
                gp = A + (size_t)(m0 + ch * 16 + cr) * 256 + k0 + cc;
                l = At + ch * 512;
            } else if (ch < 12) {
                const int c2 = ch - 8;
                gp = Bt + (size_t)(ng0 + c2 * 16 + cr) * 256 + k0 + cc;
                l = Bg + c2 * 512;
            } else {
                const int c2 = ch - 12;
                gp = Bt + (size_t)(ng0 + 256 + c2 * 16 + cr) * 256 + k0 + cc;
                l = Bv + c2 * 512;
            }
            gl_lds16(gp, l);
        }
        __syncthreads();

        short8 af[TM], bg[TN], bv[TN];
        #pragma unroll
        for (int mi = 0; mi < TM; ++mi)
            af[mi] = *(const short8*)&At[(mw + mi * 16 + l15) * 32 + kq];
        #pragma unroll
        for (int nj = 0; nj < TN; ++nj) {
            bg[nj] = *(const short8*)&Bg[(nj * 16 + l15) * 32 + kq];
            bv[nj] = *(const short8*)&Bv[(nj * 16 + l15) * 32 + kq];
        }
        #pragma unroll
        for (int mi = 0; mi < TM; ++mi)
            #pragma unroll
            for (int nj = 0; nj < TN; ++nj) {
                accg[mi][nj] = __builtin_amdgcn_mfma_f32_16x16x32_bf16(af[mi], bg[nj], accg[mi][nj], 0, 0, 0);
                accv[mi][nj] = __builtin_amdgcn_mfma_f32_16x16x32_bf16(af[mi], bv[nj], accv[mi][nj], 0, 0, 0);
            }
        __syncthreads();
    }

    const int crow = (lane >> 4) * 4;
    #pragma unroll
    for (int mi = 0; mi < TM; ++mi) {
        #pragma unroll
        for (int nj = 0; nj < TN; ++nj) {
            const int n = ng0 + nj * 16 + l15;
            const float bg_ = bF[256 + n], bv_ = bF[512 + n];
            #pragma unroll
            for (int r = 0; r < 4; ++r) {
                const int m = m0 + mw + mi * 16 + crow + r;
                const float gate = accg[mi][nj][r] + bg_;
                const float val = accv[mi][nj][r] + bv_;
                const float ge = 0.5f * gate * (1.0f + erff(gate * 0.70710678118654752f));
                g[(size_t)m * 256 + n] = f2us(ge * val);
            }
        }
    }
}

// ---------------------------------------------------------------------------
// Neighborhood attention (verified R4): masked dense MFMA over 14x14 halo.
// ---------------------------------------------------------------------------
__global__ __launch_bounds__(256) void attn_kernel(const ushort16* __restrict__ qkv,
                                                   ushort16* __restrict__ ao) {
    __shared__ ushort16 smem[40208];
    ushort16* const KS = smem;
    ushort16* const VT = smem + 12544;
    ushort16* const PL = smem + 26880;

    const int tid = threadIdx.x, lane = tid & 63, wid = tid >> 6;
    const int l15 = lane & 15, kq8 = (lane >> 4) * 8;
    const int bid = blockIdx.x;
    const int h = bid & 3;
    const int t = (bid >> 2) & 63;
    const int b = bid >> 8;
    const int ty0 = (t >> 3) * 8, tx0 = (t & 7) * 8;
    const int hby = min(max(ty0 - 3, 0), 50);
    const int hbx = min(max(tx0 - 3, 0), 50);
    const int hcol = h * 64;

    const int qpl = wid * 16 + l15;
    const int qpy = ty0 + (qpl >> 3), qpx = tx0 + (qpl & 7);
    const size_t qoff = (size_t)(b * 4096 + qpy * 64 + qpx) * 768 + hcol + kq8;
    const short8 af0 = *(const short8*)&qkv[qoff];
    const short8 af1 = *(const short8*)&qkv[qoff + 32];

    for (int it = tid; it < 3136; it += 256) {
        const bool isK = it < 1568;
        const int task = isK ? it : it - 1568;
        const int key = task >> 3, oct = task & 7;
        const int pix = b * 4096 + (hby + key / 14) * 64 + hbx + key % 14;
        const uint4 d = *(const uint4*)&qkv[(size_t)pix * 768 + (isK ? 256 : 512) + hcol + oct * 8];
        if (isK) {
            uint32* dst = (uint32*)&KS[(oct >> 2) * 6272 + key * 32 + (oct & 3) * 8];
            dst[0] = d.x; dst[1] = d.y; dst[2] = d.z; dst[3] = d.w;
        } else {
            const ushort16* s8 = (const ushort16*)&d;
            #pragma unroll
            for (int j = 0; j < 8; ++j) VT[(oct * 8 + j) * 224 + key] = s8[j];
        }
    }
    for (int it = tid; it < 1792; it += 256)
        VT[(it / 28) * 224 + 196 + (it % 28)] = 0;
    __syncthreads();

    floatx4 acc[13];
    #pragma unroll
    for (int nt = 0; nt < 13; ++nt) {
        const int krow = (nt * 16 + l15) * 32 + kq8;
        const short8 bf0 = *(const short8*)&KS[krow];
        const short8 bf1 = *(const short8*)&KS[6272 + krow];
        floatx4 a = {0.0f, 0.0f, 0.0f, 0.0f};
        a = __builtin_amdgcn_mfma_f32_16x16x32_bf16(af0, bf0, a, 0, 0, 0);
        a = __builtin_amdgcn_mfma_f32_16x16x32_bf16(af1, bf1, a, 0, 0, 0);
        acc[nt] = a;
    }

    int kyA[13], kxA[13];
    #pragma unroll
    for (int nt = 0; nt < 13; ++nt) {
        const int kidx = nt * 16 + l15;
        kyA[nt] = hby + kidx / 14;
        kxA[nt] = hbx + kidx % 14;
    }

    const int crow = (lane >> 4) * 4;
    float rs[4];
    #pragma unroll
    for (int r = 0; r < 4; ++r) {
        const int pl = wid * 16 + crow + r;
        const int py = ty0 + (pl >> 3), px = tx0 + (pl & 7);
        const int sy = min(max(py - 3, 0), 57), sx = min(max(px - 3, 0), 57);
        float lv[13];
        float mx = -1e30f;
        #pragma unroll
        for (int nt = 0; nt < 13; ++nt) {
            const int kidx = nt * 16 + l15;
            const bool valid = (kidx < 196) &&
                               ((unsigned)(kyA[nt] - sy) < 7u) &&
                               ((unsigned)(kxA[nt] - sx) < 7u);
            lv[nt] = valid ? acc[nt][r] * 0.125f : -1e30f;
            mx = fmaxf(mx, lv[nt]);
        }
        #pragma unroll
        for (int off = 1; off < 16; off <<= 1) mx = fmaxf(mx, __shfl_xor(mx, off));
        float sme = 0.0f;
        #pragma unroll
        for (int nt = 0; nt < 13; ++nt) {
            const float e = exp2f((lv[nt] - mx) * 1.4426950408889634f);
            lv[nt] = e;
            sme += e;
        }
        #pragma unroll
        for (int off = 1; off < 16; off <<= 1) sme += __shfl_xor(sme, off);
        rs[r] = 1.0f / sme;
        #pragma unroll
        for (int nt = 0; nt < 13; ++nt)
            PL[pl * 208 + nt * 16 + l15] = f2us(lv[nt]);
    }
    __syncthreads();

    floatx4 oacc[4] = {};
    #pragma unroll
    for (int kc = 0; kc < 7; ++kc) {
        const short8 af = *(const short8*)&PL[(wid * 16 + l15) * 208 + kc * 32 + kq8];
        #pragma unroll
        for (int nd = 0; nd < 4; ++nd) {
            const short8 bf = *(const short8*)&VT[(nd * 16 + l15) * 224 + kc * 32 + kq8];
            oacc[nd] = __builtin_amdgcn_mfma_f32_16x16x32_bf16(af, bf, oacc[nd], 0, 0, 0);
        }
    }
    #pragma unroll
    for (int r = 0; r < 4; ++r) {
        const int pl = wid * 16 + crow + r;
        const int py = ty0 + (pl >> 3), px = tx0 + (pl & 7);
        const size_t o = (size_t)(b * 4096 + py * 64 + px) * 256 + hcol;
        #pragma unroll
        for (int nd = 0; nd < 4; ++nd)
            ao[o + nd * 16 + l15] = f2us(oacc[nd][r] * rs[r]);
    }
}

// ---------------------------------------------------------------------------
extern "C" void kernel_launch(void* const* d_in, const int* in_sizes, int n_in,
                              void* d_out, int out_size, void* d_ws, size_t ws_size,
                              hipStream_t stream) {
    const void* x   = d_in[0];
    const void* n1w = d_in[1];
    const void* n2w = d_in[2];
    WSrc ws_src{d_in[3], d_in[4], d_in[6], d_in[8], d_in[5], d_in[7], d_in[9]};

    char* ws = (char*)d_ws;
    int*      flag = (int*)ws;
    ushort16* wT   = (ushort16*)(ws + 4096);
    float*    bF   = (float*)(ws + 4096 + 458752 * 2);
    ushort16* h    = (ushort16*)(ws + (1 << 20));           // h, then y
    ushort16* qkv  = (ushort16*)(ws + (5 << 20));
    ushort16* ao   = (ushort16*)(ws + (size_t)(17 << 20));  // ao, then g
    float*    x1   = (float*)(ws + (size_t)(21 << 20));

    ushort16* wqkvT  = wT;
    ushort16* wprojT = wT + 196608;
    ushort16* ff1wT  = wT + 262144;
    ushort16* ff2wT  = wT + 393216;

    detect_kernel<<<1, 64, 0, stream>>>((const ushort16*)x, flag);
    cvt_kernel<<<113, 256, 0, stream>>>(ws_src, wT, bF, flag);
    // h = bf16(rope2d(rmsnorm(x, n1w)))
    rms1_kernel<<<2048, 256, 0, stream>>>(x, n1w, h, flag);
    // qkv = h @ w_qkv
    gemm_mfma<128, 128, 2, 2, 0><<<dim3(6, 64), 256, 0, stream>>>(h, wqkvT, nullptr, nullptr, qkv, 768, flag);
    // ao = neighborhood_attn(qkv)
    attn_kernel<<<512, 256, 0, stream>>>(qkv, ao);
    // x1 = x + ao @ w_proj + b_proj (fp32); y = rmsnorm(x1, n2w) (bf16, into h)
    gemm_proj_rms<<<256, 256, 0, stream>>>(ao, wprojT, bF, x, n2w, x1, h, flag);
    // g = gelu(y@ff1_w + b [gate]) * (y@ff1_w + b [value])   (bf16, into ao)
    gemm_ff1_geglu<<<dim3(4, 64), 256, 0, stream>>>(h, ff1wT, bF, ao, flag);
    // out = x1 + g @ ff2_w + ff2_b
    gemm_mfma<64, 128, 1, 4, 3><<<dim3(2, 128), 256, 0, stream>>>(ao, ff2wT, bF + 768, x1, d_out, 256, flag);
}